// Round 1
// baseline (106.142 us; speedup 1.0000x reference)
//
#include <hip/hip_runtime.h>
#include <hip/hip_bf16.h>

#define N_IN   256
#define N_HID  128
#define N_ELEM 5
#define BM     64
#define A_PAD  264   // bf16 elems per LDS row (256 + 8) -> breaks bank conflicts
#define H_PAD  132   // f32 elems per LDS row for hidden

typedef __attribute__((ext_vector_type(8))) short  short8;
typedef __attribute__((ext_vector_type(4))) short  short4v;
typedef __attribute__((ext_vector_type(4))) float  float4v;

__device__ __forceinline__ int expert_of(int z) {
    // 1->0 (H), 6->1 (C), 7->2 (N), 8->3 (O), 16->4 (S)
    return (z == 1) ? 0 : (z == 6) ? 1 : (z == 7) ? 2 : (z == 8) ? 3 : 4;
}

// fp32 -> bf16 round-to-nearest-even, as raw short
__device__ __forceinline__ short f2bf(float f) {
    union { float f; unsigned u; } c; c.f = f;
    unsigned r = (c.u + 0x7fffu + ((c.u >> 16) & 1u)) >> 16;
    return (short)r;
}

// ---------------- prep: W1 fp32 -> bf16 (same [e][hid][k] layout) --------------
__global__ void prep_w_kernel(const float* __restrict__ W1, short* __restrict__ W1b, int n) {
    int i = (blockIdx.x * blockDim.x + threadIdx.x) * 4;
    if (i >= n) return;
    float4v f = *(const float4v*)(W1 + i);
    short4v s;
    s[0] = f2bf(f[0]); s[1] = f2bf(f[1]); s[2] = f2bf(f[2]); s[3] = f2bf(f[3]);
    *(short4v*)(W1b + i) = s;
}

// ---------------- histogram ----------------------------------------------------
__global__ void hist_kernel(const int* __restrict__ z, int n, int* __restrict__ counts) {
    __shared__ int cnt[N_ELEM];
    if (threadIdx.x < N_ELEM) cnt[threadIdx.x] = 0;
    __syncthreads();
    int i = blockIdx.x * blockDim.x + threadIdx.x;
    if (i < n) atomicAdd(&cnt[expert_of(z[i])], 1);
    __syncthreads();
    if (threadIdx.x < N_ELEM && cnt[threadIdx.x]) atomicAdd(&counts[threadIdx.x], cnt[threadIdx.x]);
}

// ---------------- tile table + cursor init ------------------------------------
__global__ void build_tiles_kernel(const int* __restrict__ counts, int* __restrict__ cursor,
                                   int* __restrict__ nTiles, int* __restrict__ tileE,
                                   int* __restrict__ tileStart, int* __restrict__ tileRows) {
    __shared__ int soff[N_ELEM], scnt[N_ELEM], stp[N_ELEM + 1];
    if (threadIdx.x == 0) {
        int o = 0, tp = 0;
        for (int e = 0; e < N_ELEM; ++e) {
            int c = counts[e];
            scnt[e] = c; soff[e] = o; cursor[e] = o; stp[e] = tp;
            o += c; tp += (c + BM - 1) / BM;
        }
        stp[N_ELEM] = tp;
        nTiles[0] = tp;
    }
    __syncthreads();
    int total = stp[N_ELEM];
    for (int t = threadIdx.x; t < total; t += blockDim.x) {
        int e = 0;
        while (e < N_ELEM - 1 && t >= stp[e + 1]) ++e;
        int i = t - stp[e];
        tileE[t] = e;
        tileStart[t] = soff[e] + i * BM;
        tileRows[t] = min(BM, scnt[e] - i * BM);
    }
}

// ---------------- scatter atoms into expert-sorted perm ------------------------
__global__ void scatter_kernel(const int* __restrict__ z, int n,
                               int* __restrict__ cursor, int* __restrict__ perm) {
    __shared__ int cnt[N_ELEM], cur[N_ELEM], base[N_ELEM];
    int tid = threadIdx.x;
    if (tid < N_ELEM) { cnt[tid] = 0; cur[tid] = 0; }
    __syncthreads();
    int i = blockIdx.x * blockDim.x + tid;
    int e = -1;
    if (i < n) { e = expert_of(z[i]); atomicAdd(&cnt[e], 1); }
    __syncthreads();
    if (tid < N_ELEM) base[tid] = cnt[tid] ? atomicAdd(&cursor[tid], cnt[tid]) : 0;
    __syncthreads();
    if (e >= 0) {
        int r = atomicAdd(&cur[e], 1);
        perm[base[e] + r] = i;
    }
}

// ---------------- fused grouped GEMM: x -> silu(W1 x + b1) -> W2 . h + b2 ------
__launch_bounds__(256)
__global__ void mlp_kernel(const float* __restrict__ X, const short* __restrict__ W1b,
                           const float* __restrict__ B1, const float* __restrict__ W2,
                           const float* __restrict__ B2, const int* __restrict__ perm,
                           const int* __restrict__ nTiles, const int* __restrict__ tileE,
                           const int* __restrict__ tileStart, const int* __restrict__ tileRows,
                           float* __restrict__ out) {
    __shared__ short Abuf[BM * A_PAD];          // 33792 B, aliased as Hbuf (f32) later
    __shared__ float w2s[N_HID];
    __shared__ int   rowIds[BM];

    int t = blockIdx.x;
    if (t >= nTiles[0]) return;
    int e = tileE[t], rs = tileStart[t], rows = tileRows[t];

    int tid  = threadIdx.x;
    int lane = tid & 63;
    int w    = tid >> 6;            // wave id 0..3, owns N columns [w*32, w*32+32)

    if (tid < N_HID) w2s[tid] = W2[e * N_HID + tid];

    // ---- prefetch B fragments straight from global (L2-resident after first touch)
    // B[k][n] = W1[e][n][k]; lane holds n = nbase+ni*16+(lane&15), k = kk*32+(lane>>4)*8 + j
    const short* Wb = W1b + e * (N_HID * N_IN);
    int bn  = w * 32 + (lane & 15);
    int bk0 = (lane >> 4) * 8;
    short8 bfrag[2][8];
#pragma unroll
    for (int ni = 0; ni < 2; ++ni)
#pragma unroll
        for (int kk = 0; kk < 8; ++kk)
            bfrag[ni][kk] = *(const short8*)(Wb + (bn + ni * 16) * N_IN + kk * 32 + bk0);

    // ---- stage A tile (gathered rows, fp32 -> bf16 in LDS)
    int row = tid >> 2, sub = tid & 3;                 // 4 threads per row
    int gid = perm[rs + (row < rows ? row : 0)];
    if (sub == 0) rowIds[row] = gid;
    const float* xr = X + (long)gid * N_IN;
#pragma unroll
    for (int i = 0; i < 16; ++i) {
        int c = (sub + 4 * i) * 4;                     // float column
        float4v f = *(const float4v*)(xr + c);
        short4v s;
        s[0] = f2bf(f[0]); s[1] = f2bf(f[1]); s[2] = f2bf(f[2]); s[3] = f2bf(f[3]);
        *(short4v*)(&Abuf[row * A_PAD + c]) = s;
    }
    __syncthreads();

    // ---- K loop: 8 steps of K=32, each wave does 4(M) x 2(N) MFMAs
    float4v acc[4][2] = {};
    int am = lane & 15, ak = (lane >> 4) * 8;
#pragma unroll
    for (int kk = 0; kk < 8; ++kk) {
        short8 a[4];
#pragma unroll
        for (int mi = 0; mi < 4; ++mi)
            a[mi] = *(const short8*)(&Abuf[(mi * 16 + am) * A_PAD + kk * 32 + ak]);
#pragma unroll
        for (int mi = 0; mi < 4; ++mi) {
            acc[mi][0] = __builtin_amdgcn_mfma_f32_16x16x32_bf16(a[mi], bfrag[0][kk], acc[mi][0], 0, 0, 0);
            acc[mi][1] = __builtin_amdgcn_mfma_f32_16x16x32_bf16(a[mi], bfrag[1][kk], acc[mi][1], 0, 0, 0);
        }
    }
    __syncthreads();   // all waves done reading Abuf before aliasing it as Hbuf

    // ---- bias + silu, write hidden to LDS (fp32)
    float* Hbuf = (float*)Abuf;                        // [BM][H_PAD]
    int hr0 = (lane >> 4) * 4;
#pragma unroll
    for (int ni = 0; ni < 2; ++ni) {
        int hc = w * 32 + ni * 16 + (lane & 15);
        float bias = B1[e * N_HID + hc];
#pragma unroll
        for (int mi = 0; mi < 4; ++mi)
#pragma unroll
            for (int r = 0; r < 4; ++r) {
                float v = acc[mi][ni][r] + bias;
                v = v / (1.0f + __expf(-v));           // silu
                Hbuf[(mi * 16 + hr0 + r) * H_PAD + hc] = v;
            }
    }
    __syncthreads();

    // ---- layer 2: y[atom] = sum_h H[atom][h] * w2[h] + b2   (4 threads per atom)
    int a2 = tid >> 2, p = tid & 3;
    float s = 0.0f;
#pragma unroll
    for (int i = 0; i < 32; ++i) {
        int hc = p + 4 * i;                            // interleaved -> ~conflict-free
        s += Hbuf[a2 * H_PAD + hc] * w2s[hc];
    }
    s += __shfl_xor(s, 1, 64);
    s += __shfl_xor(s, 2, 64);
    if (p == 0 && a2 < rows) out[rowIds[a2]] = s + B2[e];
}

// ---------------- launch -------------------------------------------------------
extern "C" void kernel_launch(void* const* d_in, const int* in_sizes, int n_in,
                              void* d_out, int out_size, void* d_ws, size_t ws_size,
                              hipStream_t stream) {
    const int*   z  = (const int*)  d_in[0];
    const float* X  = (const float*)d_in[1];
    const float* W1 = (const float*)d_in[2];
    const float* B1 = (const float*)d_in[3];
    const float* W2 = (const float*)d_in[4];
    const float* B2 = (const float*)d_in[5];
    float* out = (float*)d_out;
    int nAtoms = in_sizes[0];

    char* ws = (char*)d_ws;
    size_t off = 0;
    short* W1b = (short*)(ws + off); off += (size_t)N_ELEM * N_HID * N_IN * 2;  // 327680
    int* perm    = (int*)(ws + off); off += (size_t)nAtoms * 4;
    int* counts  = (int*)(ws + off); off += 32;
    int* cursor  = (int*)(ws + off); off += 32;
    int* nTiles  = (int*)(ws + off); off += 32;
    int maxTiles = (nAtoms + BM - 1) / BM + N_ELEM;
    int* tileE     = (int*)(ws + off); off += (size_t)maxTiles * 4;
    int* tileStart = (int*)(ws + off); off += (size_t)maxTiles * 4;
    int* tileRows  = (int*)(ws + off); off += (size_t)maxTiles * 4;

    hipMemsetAsync(counts, 0, 32, stream);

    int wElems = N_ELEM * N_HID * N_IN;
    prep_w_kernel<<<(wElems / 4 + 255) / 256, 256, 0, stream>>>(W1, W1b, wElems);

    int hb = (nAtoms + 255) / 256;
    hist_kernel<<<hb, 256, 0, stream>>>(z, nAtoms, counts);
    build_tiles_kernel<<<1, 256, 0, stream>>>(counts, cursor, nTiles, tileE, tileStart, tileRows);
    scatter_kernel<<<hb, 256, 0, stream>>>(z, nAtoms, cursor, perm);
    mlp_kernel<<<maxTiles, 256, 0, stream>>>(X, W1b, B1, W2, B2, perm,
                                             nTiles, tileE, tileStart, tileRows, out);
}